// Round 1
// baseline (218.479 us; speedup 1.0000x reference)
//
#include <hip/hip_runtime.h>

// Problem constants (fixed by the reference): B,H,W,D = 64,32,32,64; K=1024
#define NPTS   65536      // B*H*W
#define DDIM   64
#define KCODES 1024
#define QOUT_ELEMS (NPTS * DDIM)   // 4194304 quantized floats, indices follow

// Prologue: ||e_k||^2 for each code into d_ws (4 KB)
__global__ void e2_kernel(const float* __restrict__ emb, float* __restrict__ e2) {
    int k = blockIdx.x * blockDim.x + threadIdx.x;
    if (k < KCODES) {
        const float4* e4 = (const float4*)(emb + (size_t)k * DDIM);
        float s = 0.f;
        #pragma unroll
        for (int i = 0; i < DDIM / 4; ++i) {
            float4 v = e4[i];
            s = fmaf(v.x, v.x, s);
            s = fmaf(v.y, v.y, s);
            s = fmaf(v.z, v.z, s);
            s = fmaf(v.w, v.w, s);
        }
        e2[k] = s;
    }
}

// Main: block = 256 threads = 4 waves; block handles 64 points.
// Lane l of every wave owns point (blockIdx.x*64 + l); wave w covers codes
// [w*256, (w+1)*256). Embedding index is wave-uniform -> scalar (SMEM) loads.
__global__ __launch_bounds__(256, 4) void vq_kernel(
    const float* __restrict__ z,
    const float* __restrict__ emb,
    const float* __restrict__ e2,
    float* __restrict__ out)
{
    const int lane = threadIdx.x & 63;
    const int wave = __builtin_amdgcn_readfirstlane(threadIdx.x >> 6); // uniform 0..3
    const int point = blockIdx.x * 64 + lane;

    // z[point][0..63] into registers (64 VGPRs)
    float zr[DDIM];
    {
        const float4* z4 = (const float4*)(z + (size_t)point * DDIM);
        #pragma unroll
        for (int i = 0; i < DDIM / 4; ++i) {
            float4 v = z4[i];
            zr[4 * i + 0] = v.x; zr[4 * i + 1] = v.y;
            zr[4 * i + 2] = v.z; zr[4 * i + 3] = v.w;
        }
    }

    float best = 3.4e38f;
    int bestk = 0;
    const int k0 = wave * 256;
    for (int kk = 0; kk < 256; ++kk) {
        const int k = k0 + kk;                       // wave-uniform
        const float* __restrict__ ek = emb + (size_t)k * DDIM;
        float a0 = 0.f, a1 = 0.f, a2 = 0.f, a3 = 0.f;
        #pragma unroll
        for (int d = 0; d < DDIM; d += 4) {
            a0 = fmaf(zr[d + 0], ek[d + 0], a0);
            a1 = fmaf(zr[d + 1], ek[d + 1], a1);
            a2 = fmaf(zr[d + 2], ek[d + 2], a2);
            a3 = fmaf(zr[d + 3], ek[d + 3], a3);
        }
        float dot = (a0 + a1) + (a2 + a3);
        float s = fmaf(-2.f, dot, e2[k]);            // ||e||^2 - 2 z.e
        bool c = s < best;                           // strict < : first-min tie-break
        best  = c ? s : best;
        bestk = c ? k : bestk;
    }

    // Merge the 4 K-range candidates per point via LDS
    __shared__ float s_best[4][64];
    __shared__ int   s_idx[4][64];
    __shared__ int   s_final[64];
    s_best[wave][lane] = best;
    s_idx[wave][lane]  = bestk;
    __syncthreads();

    if (wave == 0) {
        float b = s_best[0][lane];
        int  bi = s_idx[0][lane];
        #pragma unroll
        for (int w = 1; w < 4; ++w) {
            float v = s_best[w][lane];
            int  vi = s_idx[w][lane];
            // ascending k ranges: strictly-less keeps lowest index on exact ties
            bool c = (v < b) || (v == b && vi < bi);
            b  = c ? v : b;
            bi = c ? vi : bi;
        }
        s_final[lane] = bi;
        out[QOUT_ELEMS + point] = (float)bi;         // indices output (as float)
    }
    __syncthreads();

    // Quantized gather+write: 64 points * 16 float4 = 1024 float4 per block
    float4* outq = (float4*)out;
    const float4* emb4 = (const float4*)emb;
    #pragma unroll
    for (int it = 0; it < 4; ++it) {
        int f  = it * 256 + threadIdx.x;   // 0..1023
        int p  = f >> 4;                   // point-in-block
        int d4 = f & 15;
        int ksel = s_final[p];
        float4 v = emb4[(size_t)ksel * (DDIM / 4) + d4];
        outq[((size_t)blockIdx.x * 64 + p) * (DDIM / 4) + d4] = v;
    }
}

extern "C" void kernel_launch(void* const* d_in, const int* in_sizes, int n_in,
                              void* d_out, int out_size, void* d_ws, size_t ws_size,
                              hipStream_t stream) {
    const float* z   = (const float*)d_in[0];
    const float* emb = (const float*)d_in[1];
    float* out = (float*)d_out;
    float* e2  = (float*)d_ws;   // 1024 floats

    e2_kernel<<<KCODES / 256, 256, 0, stream>>>(emb, e2);
    vq_kernel<<<NPTS / 64, 256, 0, stream>>>(z, emb, e2, out);
}

// Round 2
// 140.951 us; speedup vs baseline: 1.5500x; 1.5500x over previous
//
#include <hip/hip_runtime.h>

// Problem constants: B,H,W,D = 64,32,32,64 ; K=1024 ; N = B*H*W = 65536
#define NPTS   65536
#define DDIM   64
#define KCODES 1024
#define QOUT_ELEMS (NPTS * DDIM)   // quantized floats; indices follow at this offset

typedef _Float16 half8   __attribute__((ext_vector_type(8)));
typedef float    floatx16 __attribute__((ext_vector_type(16)));

// ---------------------------------------------------------------------------
// Prep: split embeddings into fp16 hi/lo and compute ||e_k||^2.
// ws layout: eh [K*D] f16 (128 KB) | el [K*D] f16 (128 KB) | e2 [K] f32 (4 KB)
// ---------------------------------------------------------------------------
__global__ void eprep_kernel(const float* __restrict__ emb,
                             _Float16* __restrict__ eh,
                             _Float16* __restrict__ el,
                             float* __restrict__ e2) {
    int k = blockIdx.x * blockDim.x + threadIdx.x;
    if (k >= KCODES) return;
    const float* e = emb + (size_t)k * DDIM;
    float s = 0.f;
    for (int d = 0; d < DDIM; ++d) {
        float v = e[d];
        s = fmaf(v, v, s);
        _Float16 h = (_Float16)v;            // RNE
        eh[(size_t)k * DDIM + d] = h;
        el[(size_t)k * DDIM + d] = (_Float16)(v - (float)h);  // exact residual split
    }
    e2[k] = s;
}

// ---------------------------------------------------------------------------
// Main: block = 256 thr = 4 waves. Waves (0,1) -> points [b*64, b*64+32),
// waves (2,3) -> points +32. Within a pair, wave handles one 512-code K-half.
// Each wave: A = (-2 z) for 32 points held in regs as hi/lo fp16 frags;
// loop 16 tiles of 32 codes: scores = e2 + A.e via 12 MFMAs (hh,hl,lh x 4 k-steps),
// fused running argmin in C-layout regs; shfl-reduce over cols; LDS merge.
// MFMA 32x32x16 f16 layouts:
//   A[m][k]: m = lane&31, k = (lane>>5)*8 + j   (8 contiguous dims)
//   B[k][n]: n = lane&31, k = (lane>>5)*8 + j
//   C/D:     col = lane&31, row = (reg&3) + 8*(reg>>2) + 4*(lane>>5)
// ---------------------------------------------------------------------------
__global__ __launch_bounds__(256, 4) void vq_kernel(
    const float* __restrict__ z,
    const float* __restrict__ emb,
    const _Float16* __restrict__ eh,
    const _Float16* __restrict__ el,
    const float* __restrict__ e2,
    float* __restrict__ out)
{
    const int tid  = threadIdx.x;
    const int lane = tid & 63;
    const int wave = __builtin_amdgcn_readfirstlane(tid >> 6);
    const int g    = wave >> 1;     // point group within block
    const int kh   = wave & 1;      // K half (codes kh*512 .. +512)
    const int col  = lane & 31;
    const int sel8 = lane >> 5;     // which 8-dim sub-chunk
    const int mypoint = blockIdx.x * 64 + g * 32 + col;

    // ---- A fragments: a = -2 z[p], split hi/lo fp16; 4 k-steps x 8 dims ----
    half8 ah[4], al[4];
    {
        const float* zrow = z + (size_t)mypoint * DDIM + sel8 * 8;
        #pragma unroll
        for (int ks = 0; ks < 4; ++ks) {
            const float4* p4 = (const float4*)(zrow + ks * 16);
            float4 v0 = p4[0], v1 = p4[1];
            float t[8] = {v0.x, v0.y, v0.z, v0.w, v1.x, v1.y, v1.z, v1.w};
            #pragma unroll
            for (int j = 0; j < 8; ++j) {
                float a = -2.0f * t[j];
                _Float16 h = (_Float16)a;
                ah[ks][j] = h;
                al[ks][j] = (_Float16)(a - (float)h);
            }
        }
    }

    float best[16];
    int   bestk[16];
    #pragma unroll
    for (int r = 0; r < 16; ++r) { best[r] = 3.4e38f; bestk[r] = 0; }

    const int kbase = kh * 512;
    for (int t = 0; t < 16; ++t) {
        const int code = kbase + t * 32 + col;           // this lane's column code
        const _Float16* ehrow = eh + (size_t)code * DDIM + sel8 * 8;
        const _Float16* elrow = el + (size_t)code * DDIM + sel8 * 8;
        half8 bh[4], bl[4];
        #pragma unroll
        for (int ks = 0; ks < 4; ++ks) {
            bh[ks] = *(const half8*)(ehrow + ks * 16);
            bl[ks] = *(const half8*)(elrow + ks * 16);
        }
        float e2v = e2[code];

        floatx16 acc;
        #pragma unroll
        for (int r = 0; r < 16; ++r) acc[r] = e2v;       // C init: ||e||^2 per col
        #pragma unroll
        for (int ks = 0; ks < 4; ++ks) {
            acc = __builtin_amdgcn_mfma_f32_32x32x16_f16(ah[ks], bh[ks], acc, 0, 0, 0);
            acc = __builtin_amdgcn_mfma_f32_32x32x16_f16(ah[ks], bl[ks], acc, 0, 0, 0);
            acc = __builtin_amdgcn_mfma_f32_32x32x16_f16(al[ks], bh[ks], acc, 0, 0, 0);
        }
        // running argmin; tiles ascend in k, strict < keeps lowest k on ties
        #pragma unroll
        for (int r = 0; r < 16; ++r) {
            bool c = acc[r] < best[r];
            best[r]  = c ? acc[r] : best[r];
            bestk[r] = c ? code   : bestk[r];
        }
    }

    // ---- argmin across the 32 columns (cols ascend with lane: tie -> lower k) ----
    #pragma unroll
    for (int m = 1; m < 32; m <<= 1) {
        #pragma unroll
        for (int r = 0; r < 16; ++r) {
            float ov = __shfl_xor(best[r],  m, 64);
            int   ok = __shfl_xor(bestk[r], m, 64);
            bool c = (ov < best[r]) || (ov == best[r] && ok < bestk[r]);
            best[r]  = c ? ov : best[r];
            bestk[r] = c ? ok : bestk[r];
        }
    }

    __shared__ float s_best[4][32];
    __shared__ int   s_idx[4][32];
    __shared__ int   s_final[64];
    if ((lane & 31) == 0) {          // lanes 0 and 32 hold the reduced slots
        #pragma unroll
        for (int r = 0; r < 16; ++r) {
            int row32 = (r & 3) + 8 * (r >> 2) + 4 * sel8;
            s_best[wave][row32] = best[r];
            s_idx[wave][row32]  = bestk[r];
        }
    }
    __syncthreads();

    // ---- merge K-halves, emit indices ----
    if (tid < 64) {
        int p  = tid;
        int gg = p >> 5, rr = p & 31;
        float a = s_best[2 * gg][rr];     int ka = s_idx[2 * gg][rr];
        float b = s_best[2 * gg + 1][rr]; int kb = s_idx[2 * gg + 1][rr];
        int kf = (b < a) ? kb : ka;       // kb > ka always; strict < keeps lower k
        s_final[p] = kf;
        out[QOUT_ELEMS + (size_t)blockIdx.x * 64 + p] = (float)kf;
    }
    __syncthreads();

    // ---- quantized gather: 64 points x 16 float4, coalesced ----
    float4* outq = (float4*)out;
    const float4* emb4 = (const float4*)emb;
    #pragma unroll
    for (int it = 0; it < 4; ++it) {
        int f  = it * 256 + tid;
        int p  = f >> 4;
        int d4 = f & 15;
        int ks = s_final[p];
        outq[((size_t)blockIdx.x * 64 + p) * (DDIM / 4) + d4] =
            emb4[(size_t)ks * (DDIM / 4) + d4];
    }
}

extern "C" void kernel_launch(void* const* d_in, const int* in_sizes, int n_in,
                              void* d_out, int out_size, void* d_ws, size_t ws_size,
                              hipStream_t stream) {
    const float* z   = (const float*)d_in[0];
    const float* emb = (const float*)d_in[1];
    float* out = (float*)d_out;

    _Float16* eh = (_Float16*)d_ws;
    _Float16* el = eh + (size_t)KCODES * DDIM;
    float*    e2 = (float*)(el + (size_t)KCODES * DDIM);

    eprep_kernel<<<KCODES / 256, 256, 0, stream>>>(emb, eh, el, e2);
    vq_kernel<<<NPTS / 64, 256, 0, stream>>>(z, emb, eh, el, e2, out);
}

// Round 4
// 102.004 us; speedup vs baseline: 2.1419x; 1.3818x over previous
//
#include <hip/hip_runtime.h>

// Problem: B,H,W,D = 64,32,32,64 ; K=1024 ; N = 65536
#define NPTS   65536
#define DDIM   64
#define KCODES 1024
#define QOUT_ELEMS (NPTS * DDIM)

typedef _Float16 half8    __attribute__((ext_vector_type(8)));
typedef float    floatx16 __attribute__((ext_vector_type(16)));
typedef unsigned int uint;

#define AS1 __attribute__((address_space(1)))
#define AS3 __attribute__((address_space(3)))

// ws: ehp [0,128K) chunk-major f16 | elp [128K,256K) | e2 packed pairs [256K,260K)
#define WS_EHP   0
#define WS_ELP   (128*1024)
#define WS_E2    (256*1024)

union H8U { half8 v; uint u[4]; };

static __device__ __forceinline__ void gl_lds16(const void* g, void* l) {
    __builtin_amdgcn_global_load_lds((const AS1 uint*)g, (AS3 uint*)l, 16, 0, 0);
}

// ---------------------------------------------------------------------------
// Prep: one wave per code. fp16 hi/lo split, CHUNK-MAJOR tiles:
// tile T=k>>5, chunk j=d>>3, code-in-tile c=k&31:
//   byte off = T*4096 + j*512 + c*16 + (d&7)*2
// Also packs (e2h,e2l) per code.
// ---------------------------------------------------------------------------
__global__ void eprep_kernel(const float* __restrict__ emb, char* __restrict__ ws) {
    const int tid = threadIdx.x;
    const int w = tid >> 6, d = tid & 63;
    const int k = blockIdx.x * 4 + w;
    float v = emb[(size_t)k * DDIM + d];
    _Float16 h = (_Float16)v;
    _Float16 l = (_Float16)(v - (float)h);
    size_t off = (size_t)(k >> 5) * 4096 + (size_t)(d >> 3) * 512
               + (size_t)(k & 31) * 16 + (size_t)(d & 7) * 2;
    *(_Float16*)(ws + WS_EHP + off) = h;
    *(_Float16*)(ws + WS_ELP + off) = l;
    float s = v * v;
    #pragma unroll
    for (int m = 1; m < 64; m <<= 1) s += __shfl_xor(s, m, 64);
    if (d == 0) {
        _Float16 e2h = (_Float16)s;
        _Float16 e2l = (_Float16)(s - (float)e2h);
        unsigned short hb = *(unsigned short*)&e2h;
        unsigned short lb = *(unsigned short*)&e2l;
        ((uint*)(ws + WS_E2))[k] = (uint)hb | ((uint)lb << 16);
    }
}

// ---------------------------------------------------------------------------
// Main: grid 512, block 256 = 4 waves. Wave w owns 32 points (pgrp*128+w*32+col)
// over the FULL K=1024 (32 tiles of 32 codes) -> argmin completes in-wave.
// All 4 waves share one staged tile pair (eh+el, 8KB) per iteration.
// Per tile: 13-MFMA chain (hh x4, e2-step, hl x4, lh x4) from zero C.
// MFMA 32x32x16 f16 layouts (verified round 2, absmax 0):
//   A[m][k]: m=lane&31, k=(lane>>5)*8+j ; B same with n=lane&31 ;
//   C/D: col=lane&31, row=(r&3)+8*(r>>2)+4*(lane>>5)
// ---------------------------------------------------------------------------
__global__ __launch_bounds__(256, 3) void vq_kernel(
    const float* __restrict__ z,
    const char* __restrict__ ws_c,
    const float* __restrict__ emb,
    float* __restrict__ out)
{
    const int tid  = threadIdx.x;
    const int lane = tid & 63;
    const int w    = __builtin_amdgcn_readfirstlane(tid >> 6);
    const int col  = lane & 31;
    const int sel8 = lane >> 5;
    const int pgrp = blockIdx.x;

    __shared__ uint4 ldseh[256];     // 4KB: current tile, eh
    __shared__ uint4 ldsel[256];     // 4KB: current tile, el
    __shared__ uint  lds_e2[1024];   // 4KB: packed (e2h,e2l) all codes
    __shared__ int   s_final[128];

    // ---- A fragments: a = -2 z[pt], hi/lo fp16 ----
    const int pt = pgrp * 128 + w * 32 + col;
    half8 ah[4], al[4];
    {
        const float* zrow = z + (size_t)pt * DDIM + sel8 * 8;
        #pragma unroll
        for (int ks = 0; ks < 4; ++ks) {
            float4 u0 = *(const float4*)(zrow + ks * 16);
            float4 u1 = *(const float4*)(zrow + ks * 16 + 4);
            float tv[8] = {u0.x, u0.y, u0.z, u0.w, u1.x, u1.y, u1.z, u1.w};
            #pragma unroll
            for (int j = 0; j < 8; ++j) {
                float a = -2.0f * tv[j];
                _Float16 hh = (_Float16)a;
                ah[ks][j] = hh;
                al[ks][j] = (_Float16)(a - (float)hh);
            }
        }
    }
    // e2-step A operand: A[m][k]=1 ONLY for k=0,1 (sel8==0 lanes). sel8==1 lanes
    // MUST be zero or e2 gets double-counted (round-3 bug).
    half8 ahE;
    { H8U t0; t0.u[0] = (sel8 == 0) ? 0x3C003C00u : 0u;
      t0.u[1] = t0.u[2] = t0.u[3] = 0u; ahE = t0.v; }

    // stage all e2 pairs (4KB): one 1KB chunk per wave
    gl_lds16(ws_c + WS_E2 + w * 1024 + lane * 16, (char*)lds_e2 + w * 1024);

    const floatx16 zeroC = {};   // hoisted zero C-operand (no per-tile acc init)

    float best[16];
    int   bt[16];
    #pragma unroll
    for (int r = 0; r < 16; ++r) { best[r] = 3.4e38f; bt[r] = 0; }

    const int myoff = sel8 * 512 + col * 16;   // chunk-major frag base in tile

    for (int t = 0; t < 32; ++t) {
        __syncthreads();   // previous tile's LDS reads complete
        {
            // wave w stages 2KB: operand = w>>1 (0=eh,1=el), half = w&1
            const int opnd = w >> 1, half = w & 1;
            const char* src = ws_c + (opnd ? WS_ELP : WS_EHP)
                            + (size_t)t * 4096 + half * 2048 + lane * 16;
            char* dst = (char*)(opnd ? ldsel : ldseh) + half * 2048;
            gl_lds16(src, dst);
            gl_lds16(src + 1024, dst + 1024);
        }
        __syncthreads();   // staged tile visible (vmcnt drained before barrier)

        const char* ehb = (const char*)ldseh + myoff;
        const char* elb = (const char*)ldsel + myoff;
        half8 bh[4], bl[4];
        #pragma unroll
        for (int ks = 0; ks < 4; ++ks) {
            bh[ks] = *(const half8*)(ehb + ks * 1024);
            bl[ks] = *(const half8*)(elb + ks * 1024);
        }
        half8 bhE;
        { H8U u; u.u[0] = lds_e2[t * 32 + col];
          u.u[1] = u.u[2] = u.u[3] = 0u; bhE = u.v; }

        floatx16 acc = __builtin_amdgcn_mfma_f32_32x32x16_f16(ah[0], bh[0], zeroC, 0, 0, 0);
        acc = __builtin_amdgcn_mfma_f32_32x32x16_f16(ah[1], bh[1], acc, 0, 0, 0);
        acc = __builtin_amdgcn_mfma_f32_32x32x16_f16(ah[2], bh[2], acc, 0, 0, 0);
        acc = __builtin_amdgcn_mfma_f32_32x32x16_f16(ah[3], bh[3], acc, 0, 0, 0);
        acc = __builtin_amdgcn_mfma_f32_32x32x16_f16(ahE,  bhE,  acc, 0, 0, 0);
        acc = __builtin_amdgcn_mfma_f32_32x32x16_f16(ah[0], bl[0], acc, 0, 0, 0);
        acc = __builtin_amdgcn_mfma_f32_32x32x16_f16(ah[1], bl[1], acc, 0, 0, 0);
        acc = __builtin_amdgcn_mfma_f32_32x32x16_f16(ah[2], bl[2], acc, 0, 0, 0);
        acc = __builtin_amdgcn_mfma_f32_32x32x16_f16(ah[3], bl[3], acc, 0, 0, 0);
        acc = __builtin_amdgcn_mfma_f32_32x32x16_f16(al[0], bh[0], acc, 0, 0, 0);
        acc = __builtin_amdgcn_mfma_f32_32x32x16_f16(al[1], bh[1], acc, 0, 0, 0);
        acc = __builtin_amdgcn_mfma_f32_32x32x16_f16(al[2], bh[2], acc, 0, 0, 0);
        acc = __builtin_amdgcn_mfma_f32_32x32x16_f16(al[3], bh[3], acc, 0, 0, 0);

        #pragma unroll
        for (int r = 0; r < 16; ++r) {
            bool c = acc[r] < best[r];     // strict <: earliest tile wins ties
            best[r] = c ? acc[r] : best[r];
            bt[r]   = c ? t      : bt[r];
        }
    }

    // materialize codes; butterfly argmin across the 32 columns (within sel8 group)
    int code[16];
    #pragma unroll
    for (int r = 0; r < 16; ++r) code[r] = bt[r] * 32 + col;
    #pragma unroll
    for (int m = 1; m < 32; m <<= 1) {
        #pragma unroll
        for (int r = 0; r < 16; ++r) {
            float ov = __shfl_xor(best[r], m, 64);
            int   oc = __shfl_xor(code[r], m, 64);
            bool c = (ov < best[r]) || (ov == best[r] && oc < code[r]);
            best[r] = c ? ov : best[r];
            code[r] = c ? oc : code[r];
        }
    }
    if (col == 0) {   // lanes 0 and 32: 16 rows each
        #pragma unroll
        for (int r = 0; r < 16; ++r) {
            int row = (r & 3) + 8 * (r >> 2) + 4 * sel8;
            s_final[w * 32 + row] = code[r];
        }
    }
    __syncthreads();

    // indices (coalesced) + quantized gather: 128 pts x 16 float4
    if (tid < 128)
        out[QOUT_ELEMS + (size_t)pgrp * 128 + tid] = (float)s_final[tid];
    float4* outq = (float4*)out;
    const float4* emb4 = (const float4*)emb;
    #pragma unroll
    for (int it = 0; it < 8; ++it) {
        int f  = it * 256 + tid;
        int p  = f >> 4;
        int d4 = f & 15;
        int ks = s_final[p];
        outq[((size_t)pgrp * 128 + p) * (DDIM / 4) + d4] =
            emb4[(size_t)ks * (DDIM / 4) + d4];
    }
}

extern "C" void kernel_launch(void* const* d_in, const int* in_sizes, int n_in,
                              void* d_out, int out_size, void* d_ws, size_t ws_size,
                              hipStream_t stream) {
    const float* z   = (const float*)d_in[0];
    const float* emb = (const float*)d_in[1];
    float* out = (float*)d_out;
    char* ws = (char*)d_ws;

    eprep_kernel<<<KCODES / 4, 256, 0, stream>>>(emb, ws);
    vq_kernel<<<NPTS / 128, 256, 0, stream>>>(z, ws, emb, out);
}